// Round 1
// baseline (268.853 us; speedup 1.0000x reference)
//
#include <hip/hip_runtime.h>

#define T_TOK 1024
#define H_DIM 1024
#define I_DIM 4096
#define NE 8

typedef __attribute__((ext_vector_type(8))) short bf16x8;
typedef __attribute__((ext_vector_type(4))) float f32x4;
typedef __attribute__((ext_vector_type(8))) unsigned short us8;
typedef __attribute__((ext_vector_type(4))) short s16x4;

__device__ __forceinline__ unsigned short f2bf(float x) {
  union { float f; unsigned u; } v; v.f = x;
  unsigned r = v.u + 0x7fffu + ((v.u >> 16) & 1u);  // RNE
  return (unsigned short)(r >> 16);
}

// ---------------- routing: softmax top-2 + renormalize ----------------
__global__ void k_route(const float* __restrict__ gates, int* __restrict__ counts,
                        int* __restrict__ tok_idx, float* __restrict__ tok_w) {
  int t = blockIdx.x * blockDim.x + threadIdx.x;
  if (t >= T_TOK) return;
  float g[NE];
#pragma unroll
  for (int e = 0; e < NE; ++e) g[e] = gates[t * NE + e];
  int i1 = 0; float g1 = g[0];
#pragma unroll
  for (int e = 1; e < NE; ++e) if (g[e] > g1) { g1 = g[e]; i1 = e; }
  int i2 = -1; float g2 = -1e30f;
#pragma unroll
  for (int e = 0; e < NE; ++e) if (e != i1 && g[e] > g2) { g2 = g[e]; i2 = e; }
  // softmax then renormalize over top-2 == softmax over {g1,g2}
  float wa = 1.0f / (1.0f + expf(g2 - g1));
  float wb = 1.0f - wa;
  int s1 = atomicAdd(&counts[i1], 1);
  tok_idx[i1 * T_TOK + s1] = t;
  tok_w[i1 * T_TOK + s1] = wa;
  int s2 = atomicAdd(&counts[i2], 1);
  tok_idx[i2 * T_TOK + s2] = t;
  tok_w[i2 * T_TOK + s2] = wb;
}

// ---------------- pack token copies -> compact bf16 rows ----------------
__global__ void k_pack(const float* __restrict__ hs, const int* __restrict__ counts,
                       const int* __restrict__ tok_idx, const float* __restrict__ tok_w,
                       unsigned short* __restrict__ xpack, int* __restrict__ row_tok,
                       float* __restrict__ row_w) {
  int e = blockIdx.x >> 10, slot = blockIdx.x & 1023;
  if (slot >= counts[e]) return;
  int off = 0;
#pragma unroll
  for (int i = 0; i < NE; ++i) if (i < e) off += counts[i];
  int row = off + slot;
  int tok = tok_idx[e * T_TOK + slot];
  if (threadIdx.x == 0) { row_tok[row] = tok; row_w[row] = tok_w[e * T_TOK + slot]; }
  float4 v = ((const float4*)(hs + (size_t)tok * H_DIM))[threadIdx.x];
  ushort4 o = make_ushort4(f2bf(v.x), f2bf(v.y), f2bf(v.z), f2bf(v.w));
  ((ushort4*)(xpack + (size_t)row * H_DIM))[threadIdx.x] = o;
}

// ---------------- grouped GEMM1 + SwiGLU ----------------
// C-tile: BM=64 token rows x 128 B-rows (64 gate + 64 up, interleaved by 16-row frags)
// waves 2x2: wm in rows, wn in cols; each wave 32x64 -> acc[2][4] f32x4
#define BM 64
#define BK 64

__global__ __launch_bounds__(256, 2)
void k_gemm1(const float* __restrict__ w1, const unsigned short* __restrict__ xpack,
             const int* __restrict__ counts, unsigned short* __restrict__ act) {
  // b = g*128 + i*8 + x ; p = g*8+x (panel id, p&7 = XCD) ; mtile = i
  int b = blockIdx.x;
  int p = ((b >> 7) << 3) | (b & 7);
  int mtile = (b >> 3) & 15;
  int e = p >> 6;
  int ntile = p & 63;
  int cnt = counts[e];
  int m0 = mtile * BM;
  if (m0 >= cnt) return;
  int off = 0;
#pragma unroll
  for (int i = 0; i < NE; ++i) if (i < e) off += counts[i];
  int n0 = ntile * 64;

  __shared__ __align__(16) short As[BM * BK];
  __shared__ __align__(16) short Bs[128 * BK];

  int tid = threadIdx.x;
  int lane = tid & 63, wid = tid >> 6;
  int wm = wid & 1, wn = wid >> 1;
  int lr = lane & 15, lk8 = (lane >> 4) * 8;

  const float* w1e = w1 + (size_t)e * (2 * I_DIM) * H_DIM;
  const unsigned short* xb = xpack + (size_t)(off + m0) * H_DIM;

  int arow0 = tid >> 3, ack = tid & 7;   // A: 2 x 16B chunks (rows arow0, arow0+32)
  int brow0 = tid >> 4, bck = tid & 15;  // B: 8 x float4 chunks (rows brow0 + i*16)

  f32x4 acc[2][4];
#pragma unroll
  for (int i = 0; i < 2; ++i)
#pragma unroll
    for (int j = 0; j < 4; ++j) acc[i][j] = (f32x4){0.f, 0.f, 0.f, 0.f};

  us8 aReg[2];
  float4 bReg[8];

  auto loadA = [&](int k0) {
#pragma unroll
    for (int i = 0; i < 2; ++i) {
      int r = arow0 + i * 32;
      us8 z = {0, 0, 0, 0, 0, 0, 0, 0};
      aReg[i] = (m0 + r < cnt) ? *(const us8*)(xb + (size_t)r * H_DIM + k0 + ack * 8) : z;
    }
  };
  auto loadB = [&](int k0) {
#pragma unroll
    for (int i = 0; i < 8; ++i) {
      int r = brow0 + i * 16;
      // B-tile row r -> w1 row: frag parity picks gate/up, n_local = (r>>5)*16 + (r&15)
      int grow = ((r & 16) ? I_DIM : 0) + n0 + ((r >> 5) << 4) + (r & 15);
      bReg[i] = *(const float4*)(w1e + (size_t)grow * H_DIM + k0 + bck * 4);
    }
  };

  loadA(0); loadB(0);

  for (int ks = 0; ks < H_DIM / BK; ++ks) {
    __syncthreads();
#pragma unroll
    for (int i = 0; i < 2; ++i) {
      int r = arow0 + i * 32;
      *(us8*)&As[r * BK + ((ack * 8) ^ ((r & 7) << 3))] = aReg[i];
    }
#pragma unroll
    for (int i = 0; i < 8; ++i) {
      int r = brow0 + i * 16;
      float4 v = bReg[i];
      s16x4 sv = {(short)f2bf(v.x), (short)f2bf(v.y), (short)f2bf(v.z), (short)f2bf(v.w)};
      *(s16x4*)&Bs[r * BK + ((bck * 4) ^ ((r & 7) << 3))] = sv;
    }
    __syncthreads();
    if (ks + 1 < H_DIM / BK) { loadA((ks + 1) * BK); loadB((ks + 1) * BK); }
#pragma unroll
    for (int kk = 0; kk < 2; ++kk) {
      int k0 = kk * 32 + lk8;
      bf16x8 a[2], bb[4];
#pragma unroll
      for (int mr = 0; mr < 2; ++mr) {
        int r = wm * 32 + mr * 16 + lr;
        a[mr] = *(const bf16x8*)&As[r * BK + (k0 ^ ((r & 7) << 3))];
      }
#pragma unroll
      for (int nr = 0; nr < 4; ++nr) {
        int r = (wn * 4 + nr) * 16 + lr;
        bb[nr] = *(const bf16x8*)&Bs[r * BK + (k0 ^ ((r & 7) << 3))];
      }
#pragma unroll
      for (int mr = 0; mr < 2; ++mr)
#pragma unroll
        for (int nr = 0; nr < 4; ++nr)
          acc[mr][nr] = __builtin_amdgcn_mfma_f32_16x16x32_bf16(a[mr], bb[nr], acc[mr][nr], 0, 0, 0);
    }
  }

  // SwiGLU epilogue: pairs (acc[mr][2p], acc[mr][2p+1]) share the same act column
#pragma unroll
  for (int mr = 0; mr < 2; ++mr) {
#pragma unroll
    for (int pp = 0; pp < 2; ++pp) {
      f32x4 g = acc[mr][2 * pp], u = acc[mr][2 * pp + 1];
      int ncol = n0 + (wn * 2 + pp) * 16 + lr;
#pragma unroll
      for (int q = 0; q < 4; ++q) {
        int rl = wm * 32 + mr * 16 + (lane >> 4) * 4 + q;
        if (m0 + rl < cnt) {
          float gv = g[q];
          float av = gv / (1.0f + expf(-gv)) * u[q];
          act[(size_t)(off + m0 + rl) * I_DIM + ncol] = f2bf(av);
        }
      }
    }
  }
}

// ---------------- grouped GEMM2 + scale + scatter-add ----------------
__global__ __launch_bounds__(256, 2)
void k_gemm2(const float* __restrict__ w2, const unsigned short* __restrict__ act,
             const int* __restrict__ counts, const int* __restrict__ row_tok,
             const float* __restrict__ row_w, float* __restrict__ out) {
  int b = blockIdx.x;
  int p = ((b >> 7) << 3) | (b & 7);
  int mtile = (b >> 3) & 15;
  int e = p >> 3;
  int ntile = p & 7;
  int cnt = counts[e];
  int m0 = mtile * BM;
  if (m0 >= cnt) return;
  int off = 0;
#pragma unroll
  for (int i = 0; i < NE; ++i) if (i < e) off += counts[i];
  int n0 = ntile * 128;

  __shared__ __align__(16) short As[BM * BK];
  __shared__ __align__(16) short Bs[128 * BK];

  int tid = threadIdx.x;
  int lane = tid & 63, wid = tid >> 6;
  int wm = wid & 1, wn = wid >> 1;
  int lr = lane & 15, lk8 = (lane >> 4) * 8;

  const float* w2e = w2 + (size_t)e * H_DIM * I_DIM;
  const unsigned short* ab = act + (size_t)(off + m0) * I_DIM;

  int arow0 = tid >> 3, ack = tid & 7;
  int brow0 = tid >> 4, bck = tid & 15;

  f32x4 acc[2][4];
#pragma unroll
  for (int i = 0; i < 2; ++i)
#pragma unroll
    for (int j = 0; j < 4; ++j) acc[i][j] = (f32x4){0.f, 0.f, 0.f, 0.f};

  us8 aReg[2];
  float4 bReg[8];

  auto loadA = [&](int k0) {
#pragma unroll
    for (int i = 0; i < 2; ++i) {
      int r = arow0 + i * 32;
      us8 z = {0, 0, 0, 0, 0, 0, 0, 0};
      aReg[i] = (m0 + r < cnt) ? *(const us8*)(ab + (size_t)r * I_DIM + k0 + ack * 8) : z;
    }
  };
  auto loadB = [&](int k0) {
#pragma unroll
    for (int i = 0; i < 8; ++i) {
      int r = brow0 + i * 16;
      bReg[i] = *(const float4*)(w2e + (size_t)(n0 + r) * I_DIM + k0 + bck * 4);
    }
  };

  loadA(0); loadB(0);

  for (int ks = 0; ks < I_DIM / BK; ++ks) {
    __syncthreads();
#pragma unroll
    for (int i = 0; i < 2; ++i) {
      int r = arow0 + i * 32;
      *(us8*)&As[r * BK + ((ack * 8) ^ ((r & 7) << 3))] = aReg[i];
    }
#pragma unroll
    for (int i = 0; i < 8; ++i) {
      int r = brow0 + i * 16;
      float4 v = bReg[i];
      s16x4 sv = {(short)f2bf(v.x), (short)f2bf(v.y), (short)f2bf(v.z), (short)f2bf(v.w)};
      *(s16x4*)&Bs[r * BK + ((bck * 4) ^ ((r & 7) << 3))] = sv;
    }
    __syncthreads();
    if (ks + 1 < I_DIM / BK) { loadA((ks + 1) * BK); loadB((ks + 1) * BK); }
#pragma unroll
    for (int kk = 0; kk < 2; ++kk) {
      int k0 = kk * 32 + lk8;
      bf16x8 a[2], bb[4];
#pragma unroll
      for (int mr = 0; mr < 2; ++mr) {
        int r = wm * 32 + mr * 16 + lr;
        a[mr] = *(const bf16x8*)&As[r * BK + (k0 ^ ((r & 7) << 3))];
      }
#pragma unroll
      for (int nr = 0; nr < 4; ++nr) {
        int r = (wn * 4 + nr) * 16 + lr;
        bb[nr] = *(const bf16x8*)&Bs[r * BK + (k0 ^ ((r & 7) << 3))];
      }
#pragma unroll
      for (int mr = 0; mr < 2; ++mr)
#pragma unroll
        for (int nr = 0; nr < 4; ++nr)
          acc[mr][nr] = __builtin_amdgcn_mfma_f32_16x16x32_bf16(a[mr], bb[nr], acc[mr][nr], 0, 0, 0);
    }
  }

#pragma unroll
  for (int mr = 0; mr < 2; ++mr) {
#pragma unroll
    for (int q = 0; q < 4; ++q) {
      int rl = wm * 32 + mr * 16 + (lane >> 4) * 4 + q;
      if (m0 + rl >= cnt) continue;
      int grow = off + m0 + rl;
      float wgt = row_w[grow];
      float* orow = out + (size_t)row_tok[grow] * H_DIM;
#pragma unroll
      for (int nr = 0; nr < 4; ++nr) {
        int ncol = n0 + (wn * 4 + nr) * 16 + lr;
        atomicAdd(&orow[ncol], acc[mr][nr][q] * wgt);
      }
    }
  }
}

extern "C" void kernel_launch(void* const* d_in, const int* in_sizes, int n_in,
                              void* d_out, int out_size, void* d_ws, size_t ws_size,
                              hipStream_t stream) {
  const float* hs = (const float*)d_in[0];
  const float* w1 = (const float*)d_in[1];
  const float* w2 = (const float*)d_in[2];
  const float* gates = (const float*)d_in[3];
  float* out = (float*)d_out;

  char* ws = (char*)d_ws;
  int* counts = (int*)ws;                                   // 32 B
  int* tok_idx = (int*)(ws + 1024);                         // 32 KB
  float* tok_w = (float*)(ws + 1024 + 32768);               // 32 KB
  int* row_tok = (int*)(ws + 1024 + 65536);                 // 8 KB
  float* row_w = (float*)(ws + 1024 + 65536 + 8192);        // 8 KB
  unsigned short* xpack = (unsigned short*)(ws + 131072);   // 2048x1024 bf16 = 4 MB
  unsigned short* act = (unsigned short*)(ws + 131072 + 2048 * 1024 * 2);  // 2048x4096 bf16 = 16 MB

  hipMemsetAsync(counts, 0, NE * sizeof(int), stream);
  hipMemsetAsync(d_out, 0, (size_t)out_size * sizeof(float), stream);
  k_route<<<dim3(4), dim3(256), 0, stream>>>(gates, counts, tok_idx, tok_w);
  k_pack<<<dim3(NE * T_TOK), dim3(256), 0, stream>>>(hs, counts, tok_idx, tok_w, xpack, row_tok, row_w);
  k_gemm1<<<dim3(8192), dim3(256), 0, stream>>>(w1, xpack, counts, act);
  k_gemm2<<<dim3(1024), dim3(256), 0, stream>>>(w2, act, counts, row_tok, row_w, out);
}